// Round 8
// baseline (270.272 us; speedup 1.0000x reference)
//
#include <hip/hip_runtime.h>

// Problem constants: B=8, K2=9, C=1, H=256, W=1216, times=24.
#define BB 8
#define HH 256
#define WW 1216
#define TIMES 24

// KF=4 iterations fused per dispatch; 26x26 output tile, 32x32 weight region,
// 34x34 feature region (LDS row stride 35 = odd -> stride-2 lane pattern is
// 2-way/bank = free). 512 threads; each owns a HORIZONTAL pixel pair so its
// two 3x3 footprints share taps: 12 LDS reads (3 rows x 4 consecutive cols)
// instead of 18, and consecutive-col reads merge into ds_read2_b32.
// Round-7 counters showed the LDS issue pipe as the critical path (HBM 35%,
// VALU 21%, ~835 cyc of ds_read per block-iteration).
#define KF 4
#define TSZ 26
#define RSZ 32              // weight region = TSZ + 2*(KF-1)
#define FSZ 34              // feature region values per side = TSZ + 2*KF
#define FST 35              // LDS row stride (odd, bank-parity fix)
#define NT 512
#define NFPIX (FSZ*FSZ)     // 1156
#define LDSN (FSZ*FST)      // 1190 floats per buffer
#define TGX 47              // ceil(1216/26)
#define TGY 10              // ceil(256/26)
#define NTILES (TGX*TGY)    // 470 blocks

static const size_t HW = (size_t)HH * WW;

// ---------------------------------------------------------------------------
// Validity (per batch): after iteration j, feature-region pixels at inset
// >= j+1 of the 34x34 region are correct; output tile = inset KF -> correct
// after 4 iterations. Out-of-image pixels get w=0 -> stay exactly 0.
// buf[1] zeroed once (ring never written; interior overwritten at it=0
// before it=1 reads). buf[0] fully restaged per batch.
// ---------------------------------------------------------------------------
__global__ __launch_bounds__(NT, 2) void fused4_kernel(const float* __restrict__ aff,
                                                       const float* __restrict__ src,
                                                       float* __restrict__ dst) {
    __shared__ float buf[2][LDSN];
    const int t    = threadIdx.x;
    const int tile = blockIdx.x;               // 0..469
    const int ty   = tile / TGX, tx = tile - ty * TGX;
    const int x0   = tx * TSZ,   y0 = ty * TSZ;

    // This thread's horizontal pixel pair: (wy, wxp) and (wy, wxp+1).
    const int wy  = t >> 4;                    // 0..31
    const int wxp = (t & 15) * 2;              // 0,2,...,30
    const int gy  = y0 - (KF - 1) + wy;
    const int gx0 = x0 - (KF - 1) + wxp;
    const int gx1 = gx0 + 1;
    const bool iny = (unsigned)gy < (unsigned)HH;
    const bool in0 = iny && (unsigned)gx0 < (unsigned)WW;
    const bool in1 = iny && (unsigned)gx1 < (unsigned)WW;
    const long woff0 = (long)gy * WW + gx0;    // deref'd only if in0/in1
    const long woff1 = woff0 + 1;
    const int  tbase = wy * FST + wxp;         // tap base: row wy, col wxp
    const int  cw0   = (wy + 1) * FST + (wxp + 1);  // write addr of pixel 0

    // Feature-region staging slots (3 per thread), geometry fixed.
    long foff[3]; bool fok[3]; int flds[3];
#pragma unroll
    for (int r = 0; r < 3; ++r) {
        int p  = t + r * NT;
        int fy = p / FSZ, fx = p - fy * FSZ;
        int gfy = y0 - KF + fy, gfx = x0 - KF + fx;
        fok[r]  = (p < NFPIX) && (unsigned)gfy < (unsigned)HH && (unsigned)gfx < (unsigned)WW;
        foff[r] = (long)gfy * WW + gfx;
        flds[r] = fy * FST + fx;
    }

    // buf[1]: zero once (ring must stay 0; interior rewritten each batch).
#pragma unroll
    for (int r = 0; r < 3; ++r) {
        int p = t + r * NT;
        if (p < LDSN) buf[1][p] = 0.0f;
    }

    // Prologue: batch-0 affinity + feature into registers.
    float a0[9], a1[9], f[3];
#pragma unroll
    for (int n = 0; n < 9; ++n) {
        a0[n] = in0 ? aff[woff0 + (long)n * (long)HW] : 0.0f;
        a1[n] = in1 ? aff[woff1 + (long)n * (long)HW] : 0.0f;
    }
#pragma unroll
    for (int r = 0; r < 3; ++r) f[r] = fok[r] ? src[foff[r]] : 0.0f;

    for (int b = 0; b < BB; ++b) {
        const size_t base = (size_t)b * HW;

        // Normalize current batch's weights.
        float w0[9], w1[9];
        {
            float s0 = 0.0f, s1 = 0.0f;
#pragma unroll
            for (int n = 0; n < 9; ++n) {
                a0[n] = fabsf(a0[n]); a1[n] = fabsf(a1[n]);
                s0 += a0[n]; s1 += a1[n];
            }
            float i0 = in0 ? (1.0f / s0) : 0.0f;   // out-of-image: weights 0
            float i1 = in1 ? (1.0f / s1) : 0.0f;
#pragma unroll
            for (int n = 0; n < 9; ++n) { w0[n] = a0[n] * i0; w1[n] = a1[n] * i1; }
        }

        // Issue next batch's prefetch now; its vmcnt wait lands at the
        // register rotate AFTER the LDS phase -> HBM latency hidden.
        float an0[9], an1[9], fn[3];
        if (b + 1 < BB) {
            const float* ap = aff + (size_t)(b + 1) * 9 * HW;
            const float* sp = src + (size_t)(b + 1) * HW;
#pragma unroll
            for (int n = 0; n < 9; ++n) {
                an0[n] = in0 ? ap[woff0 + (long)n * (long)HW] : 0.0f;
                an1[n] = in1 ? ap[woff1 + (long)n * (long)HW] : 0.0f;
            }
#pragma unroll
            for (int r = 0; r < 3; ++r) fn[r] = fok[r] ? sp[foff[r]] : 0.0f;
        }

        // Stage this batch's feature region into buf[0] (ring included).
#pragma unroll
        for (int r = 0; r < 3; ++r) {
            int p = t + r * NT;
            if (p < NFPIX) buf[0][flds[r]] = f[r];
        }
        __syncthreads();

        float acc0 = 0.0f, acc1 = 0.0f;
#pragma unroll
        for (int it = 0; it < KF; ++it) {
            const float* bc = buf[it & 1];
            float*       bn = buf[(it & 1) ^ 1];
            // 12 shared taps: rows wy..wy+2, cols wxp..wxp+3 (const offsets
            // from one base -> ds_read2_b32-mergeable, 2-way banks at FST=35).
            const float* bp = bc + tbase;
            float r00 = bp[0],       r01 = bp[1],       r02 = bp[2],       r03 = bp[3];
            float r10 = bp[FST],     r11 = bp[FST+1],   r12 = bp[FST+2],   r13 = bp[FST+3];
            float r20 = bp[2*FST],   r21 = bp[2*FST+1], r22 = bp[2*FST+2], r23 = bp[2*FST+3];
            float p0, p1;
            p0  = w0[0]*r00 + w0[1]*r01 + w0[2]*r02;
            p0 += w0[3]*r10 + w0[4]*r11 + w0[5]*r12;
            p0 += w0[6]*r20 + w0[7]*r21 + w0[8]*r22;
            p1  = w1[0]*r01 + w1[1]*r02 + w1[2]*r03;
            p1 += w1[3]*r11 + w1[4]*r12 + w1[5]*r13;
            p1 += w1[6]*r21 + w1[7]*r22 + w1[8]*r23;
            acc0 = p0; acc1 = p1;
            if (it < KF - 1) {              // last iter: straight to global
                bn[cw0]     = p0;
                bn[cw0 + 1] = p1;
                __syncthreads();
            }
        }

        // Output owned pixels (inside 26x26 tile and image).
        if ((unsigned)(wy - (KF - 1)) < TSZ) {
            if ((unsigned)(wxp     - (KF - 1)) < TSZ && in0)
                dst[base + (size_t)gy * WW + gx0] = acc0;
            if ((unsigned)(wxp + 1 - (KF - 1)) < TSZ && in1)
                dst[base + (size_t)gy * WW + gx1] = acc1;
        }

        // Rotate prefetch registers (vmcnt wait lands here).
        if (b + 1 < BB) {
#pragma unroll
            for (int n = 0; n < 9; ++n) { a0[n] = an0[n]; a1[n] = an1[n]; }
#pragma unroll
            for (int r = 0; r < 3; ++r) f[r] = fn[r];
        }
    }
}

// ---------------------------------------------------------------------------
// 24 iterations = 6 launches (each advances all batches by KF=4 steps).
// Ping-pong: ws -> out -> ws ... -> out (6 even -> final lands in d_out).
// ---------------------------------------------------------------------------
extern "C" void kernel_launch(void* const* d_in, const int* in_sizes, int n_in,
                              void* d_out, int out_size, void* d_ws, size_t ws_size,
                              hipStream_t stream) {
    const float* affinity = (const float*)d_in[0];
    const float* feature  = (const float*)d_in[1];
    // d_in[2] is `times` (== 24 per setup_inputs); hard-coded as TIMES.

    float* bufA = (float*)d_ws;     // scratch feature plane (10 MB)
    float* bufO = (float*)d_out;

    const int NL = TIMES / KF;      // 6

    const float* src = feature;
    for (int l = 0; l < NL; ++l) {
        float* dst = (l & 1) ? bufO : bufA;   // l=5 (last) -> bufO == d_out
        fused4_kernel<<<dim3(NTILES, 1, 1), dim3(NT, 1, 1), 0, stream>>>(affinity, src, dst);
        src = dst;
    }
}

// Round 9
// 254.422 us; speedup vs baseline: 1.0623x; 1.0623x over previous
//
#include <hip/hip_runtime.h>

// Problem constants: B=8, K2=9, C=1, H=256, W=1216, times=24.
#define BB 8
#define HH 256
#define WW 1216
#define TIMES 24

// KF=4 iterations fused per dispatch; 26x26 output tile, 32x32 weight region,
// 34x34 feature region; 512 threads x vertical pixel pair (round-7 structure,
// the best so far). Round-9 change: software pipeline that actually works --
// raw lgkm-only barriers (global loads stay in flight across them), 3-buffer
// LDS rotation (S staged / P,Q ping-pong) so next batch's feature is written
// into S mid-phase, and sched_barrier pinning so the prefetch isn't sunk
// (round 7/8: VGPR_Count 44-48 proved the compiler sank the prefetch loads
// to their use point; __syncthreads also drains vmcnt at every barrier).
#define KF 4
#define TSZ 26
#define FSZ 34
#define NT 512
#define NFPIX (FSZ*FSZ)     // 1156
#define TGX 47              // ceil(1216/26)
#define TGY 10              // ceil(256/26)
#define NTILES (TGX*TGY)    // 470 blocks, all co-resident at 2/CU

static const size_t HW = (size_t)HH * WW;

// LDS-only barrier: does NOT drain vmcnt -> prefetch loads cross freely.
#define LDS_BARRIER() do { asm volatile("s_waitcnt lgkmcnt(0)" ::: "memory"); \
                           __builtin_amdgcn_s_barrier(); } while (0)

// One stencil application for this thread's vertical pixel pair.
// tb0/tb1 = top-left tap addresses; all 18 reads are immediate offsets
// from two base addresses (conflict-free: half-waves read consecutive
// dwords, 2 lanes/bank = free).
#define STEP(BC, o0, o1) do {                                              \
    const float* _c0 = (BC) + tb0;                                         \
    const float* _c1 = (BC) + tb1;                                         \
    (o0) = w0[0]*_c0[0]       + w0[1]*_c0[1]         + w0[2]*_c0[2]        \
         + w0[3]*_c0[FSZ]     + w0[4]*_c0[FSZ+1]     + w0[5]*_c0[FSZ+2]    \
         + w0[6]*_c0[2*FSZ]   + w0[7]*_c0[2*FSZ+1]   + w0[8]*_c0[2*FSZ+2]; \
    (o1) = w1[0]*_c1[0]       + w1[1]*_c1[1]         + w1[2]*_c1[2]        \
         + w1[3]*_c1[FSZ]     + w1[4]*_c1[FSZ+1]     + w1[5]*_c1[FSZ+2]    \
         + w1[6]*_c1[2*FSZ]   + w1[7]*_c1[2*FSZ+1]   + w1[8]*_c1[2*FSZ+2]; \
} while (0)

// ---------------------------------------------------------------------------
// Validity (per batch): it0 S->P (inset>=1), it1 P->Q (>=2), it2 Q->P (>=3),
// it3 P->regs (>=4 = output tile). P/Q rings zeroed once and never written
// (all writes interior); rim values computed from zero rings never reach the
// output (same trapezoid argument as rounds 5-8, which passed).
// Race audit: S last read at it0, rewritten after it1-barrier (it0 reads
// drained by lgkmcnt(0) at it0-barrier). S-writes drained at it2-barrier,
// next read after final barrier. it3's P-reads drained at final barrier
// before next it0 writes P. All s_barriers unconditional.
// ---------------------------------------------------------------------------
__global__ __launch_bounds__(NT, 4) void fused4_kernel(const float* __restrict__ aff,
                                                       const float* __restrict__ src,
                                                       float* __restrict__ dst) {
    __shared__ float S[NFPIX], P[NFPIX], Q[NFPIX];

    const int t    = threadIdx.x;
    const int tile = blockIdx.x;               // 0..469
    const int ty   = tile / TGX, tx = tile - ty * TGX;
    const int x0   = tx * TSZ,   y0 = ty * TSZ;

    // Vertical pixel pair: (wy0, wx) and (wy0+16, wx) in the 32x32 region.
    const int wx  = t & 31;
    const int wy0 = t >> 5;                    // 0..15
    const int wy1 = wy0 + 16;
    const int gx  = x0 - (KF - 1) + wx;
    const int gy0 = y0 - (KF - 1) + wy0;
    const int gy1 = gy0 + 16;
    const bool in0 = (unsigned)gy0 < (unsigned)HH && (unsigned)gx < (unsigned)WW;
    const bool in1 = (unsigned)gy1 < (unsigned)HH && (unsigned)gx < (unsigned)WW;
    const long woff0 = (long)gy0 * WW + gx;    // deref'd only if in0/in1
    const long woff1 = (long)gy1 * WW + gx;
    const int  tb0 = wy0 * FSZ + wx;           // top-left of pixel0's 3x3
    const int  tb1 = tb0 + 16 * FSZ;
    const int  cw0 = (wy0 + 1) * FSZ + (wx + 1);
    const int  cw1 = cw0 + 16 * FSZ;

    // Feature staging slots (3 per thread, linear layout).
    int foff[3]; bool fok[3];
#pragma unroll
    for (int r = 0; r < 3; ++r) {
        int p  = t + r * NT;
        int fy = p / FSZ, fx = p - fy * FSZ;
        int gfy = y0 - KF + fy, gfx = x0 - KF + fx;
        fok[r]  = (p < NFPIX) && (unsigned)gfy < (unsigned)HH && (unsigned)gfx < (unsigned)WW;
        foff[r] = gfy * WW + gfx;
    }

    // Zero P and Q once (their rings must stay 0; interiors overwritten).
#pragma unroll
    for (int r = 0; r < 3; ++r) {
        int p = t + r * NT;
        if (p < NFPIX) { P[p] = 0.0f; Q[p] = 0.0f; }
    }

    // Prologue: batch-0 affinity into registers, feature into S.
    float a0[9], a1[9];
#pragma unroll
    for (int n = 0; n < 9; ++n) {
        a0[n] = in0 ? aff[woff0 + (long)n * (long)HW] : 0.0f;
        a1[n] = in1 ? aff[woff1 + (long)n * (long)HW] : 0.0f;
    }
#pragma unroll
    for (int r = 0; r < 3; ++r) {
        int p = t + r * NT;
        if (p < NFPIX) S[p] = fok[r] ? src[foff[r]] : 0.0f;
    }
    __syncthreads();   // prologue full drain (once)

    for (int b = 0; b < BB; ++b) {
        // Normalize this batch's weights (pure VALU, consumes a0/a1).
        float w0[9], w1[9];
        {
            float s0 = 0.0f, s1 = 0.0f;
#pragma unroll
            for (int n = 0; n < 9; ++n) {
                a0[n] = fabsf(a0[n]); s0 += a0[n];
                a1[n] = fabsf(a1[n]); s1 += a1[n];
            }
            float i0 = in0 ? (1.0f / s0) : 0.0f;   // out-of-image: weights 0
            float i1 = in1 ? (1.0f / s1) : 0.0f;
#pragma unroll
            for (int n = 0; n < 9; ++n) { w0[n] = a0[n] * i0; w1[n] = a1[n] * i1; }
        }

        // Issue next batch's loads NOW; raw barriers below don't drain vmcnt,
        // so these stay in flight under the whole LDS phase.
        float an0[9], an1[9], fn[3];
        const bool pf = (b + 1 < BB);
        if (pf) {
            const float* ap = aff + (size_t)(b + 1) * 9 * HW;
            const float* sp = src + (size_t)(b + 1) * HW;
#pragma unroll
            for (int n = 0; n < 9; ++n) {
                an0[n] = in0 ? ap[woff0 + (long)n * (long)HW] : 0.0f;
                an1[n] = in1 ? ap[woff1 + (long)n * (long)HW] : 0.0f;
            }
#pragma unroll
            for (int r = 0; r < 3; ++r) fn[r] = fok[r] ? sp[foff[r]] : 0.0f;
        }
        __builtin_amdgcn_sched_barrier(0);   // pin: loads may not sink below

        float r0, r1;
        // it0: S -> P
        STEP(S, r0, r1);
        P[cw0] = r0; P[cw1] = r1;
        LDS_BARRIER();
        // it1: P -> Q
        STEP(P, r0, r1);
        Q[cw0] = r0; Q[cw1] = r1;
        LDS_BARRIER();
        // S is free now (last read at it0): stage next batch's feature.
        // (vmcnt wait for fn lands here, covered by it0+it1.)
        if (pf) {
#pragma unroll
            for (int r = 0; r < 3; ++r) {
                int p = t + r * NT;
                if (p < NFPIX) S[p] = fn[r];
            }
        }
        // it2: Q -> P
        STEP(Q, r0, r1);
        P[cw0] = r0; P[cw1] = r1;
        LDS_BARRIER();
        // it3: P -> registers only (output goes straight to global).
        STEP(P, r0, r1);

        // Rotate affinity prefetch (vmcnt wait for an0/an1 lands here).
        if (pf) {
#pragma unroll
            for (int n = 0; n < 9; ++n) { a0[n] = an0[n]; a1[n] = an1[n]; }
        }
        LDS_BARRIER();   // drains it3 reads; next it0 may rewrite P after this

        // Store batch b's owned pixels (inside 26x26 tile and image).
        const size_t base = (size_t)b * HW;
        if ((unsigned)(wx - (KF - 1)) < (unsigned)TSZ) {
            if ((unsigned)(wy0 - (KF - 1)) < (unsigned)TSZ && in0)
                dst[base + (size_t)gy0 * WW + gx] = r0;
            if ((unsigned)(wy1 - (KF - 1)) < (unsigned)TSZ && in1)
                dst[base + (size_t)gy1 * WW + gx] = r1;
        }
    }
}

// ---------------------------------------------------------------------------
// 24 iterations = 6 launches (each advances all batches by KF=4 steps).
// Ping-pong: ws -> out -> ws ... -> out (6 even -> final lands in d_out).
// ---------------------------------------------------------------------------
extern "C" void kernel_launch(void* const* d_in, const int* in_sizes, int n_in,
                              void* d_out, int out_size, void* d_ws, size_t ws_size,
                              hipStream_t stream) {
    const float* affinity = (const float*)d_in[0];
    const float* feature  = (const float*)d_in[1];
    // d_in[2] is `times` (== 24 per setup_inputs); hard-coded as TIMES.

    float* bufA = (float*)d_ws;     // scratch feature plane (10 MB)
    float* bufO = (float*)d_out;

    const int NL = TIMES / KF;      // 6

    const float* src = feature;
    for (int l = 0; l < NL; ++l) {
        float* dst = (l & 1) ? bufO : bufA;   // l=5 (last) -> bufO == d_out
        fused4_kernel<<<dim3(NTILES, 1, 1), dim3(NT, 1, 1), 0, stream>>>(affinity, src, dst);
        src = dst;
    }
}